// Round 1
// baseline (100.995 us; speedup 1.0000x reference)
//
#include <hip/hip_runtime.h>

typedef unsigned short u16;
typedef unsigned int   u32;
typedef short  short8  __attribute__((ext_vector_type(8)));
typedef __bf16 bf16x8  __attribute__((ext_vector_type(8)));
typedef float  f32x4   __attribute__((ext_vector_type(4)));
typedef u32    u32x4   __attribute__((ext_vector_type(4)));

#define POWER_ITERS 3

// ---------- helpers ----------
__device__ __forceinline__ u16 f2bf(float f){ return __builtin_bit_cast(u16, (__bf16)f); }
__device__ __forceinline__ u32 pack2bf(float a, float b){
  return (u32)__builtin_bit_cast(u16, (__bf16)a) | ((u32)__builtin_bit_cast(u16, (__bf16)b) << 16);
}
__device__ __forceinline__ float bf2f(u16 h){ return __uint_as_float(((u32)h) << 16); }

// write-through agent-scope stores: data visible at coherence point on vmcnt retire
__device__ __forceinline__ void st_f32(float* p, float v){
  __hip_atomic_store(p, v, __ATOMIC_RELAXED, __HIP_MEMORY_SCOPE_AGENT);
}
__device__ __forceinline__ void st_i32(int* p, int v){
  __hip_atomic_store(p, v, __ATOMIC_RELAXED, __HIP_MEMORY_SCOPE_AGENT);
}
// 16B write-through store. sc0 sc1 = strongest (system) cache policy: write-through
// both cache levels, so vmcnt retire => visible at the coherence point — the same
// contract the 4B __hip_atomic_store path relied on, with 4x fewer instructions
// and full-sector payloads (fixes the ~4x WRITE_SIZE amplification).
__device__ __forceinline__ void st_wt16(void* p, u32x4 v){
  asm volatile("global_store_dwordx4 %0, %1, off sc0 sc1" :: "v"(p), "v"(v) : "memory");
}

__device__ __forceinline__ f32x4 mfma_bf16(short8 a, short8 b, f32x4 c){
  return __builtin_amdgcn_mfma_f32_16x16x32_bf16(
      __builtin_bit_cast(bf16x8, a), __builtin_bit_cast(bf16x8, b), c, 0, 0, 0);
}

// swizzled LDS address (u16 units) of element [row][k] of a 64x64 matrix
__device__ __forceinline__ int swz(int row, int k){
  return row*64 + ((((k >> 3) ^ (row & 7)) << 3) | (k & 7));
}
__device__ __forceinline__ short8 lds_frag(const u16* P, int row, int k0){
  int pos = (k0 >> 3) ^ (row & 7);
  return *(const short8*)(P + row*64 + pos*8);
}
__device__ __forceinline__ short8 g_frag(const u16* __restrict__ M, int row, int k0){
  return *(const short8*)(M + row*64 + k0);
}

// write C/D regs (matrix X) as X^T into swizzled LDS (Zt), scaled
__device__ __forceinline__ void write_CT_lds_s(u16* Pt, int lane, const f32x4 (&C)[4][4], float s){
  const int m16 = lane & 15, q = lane >> 4;
#pragma unroll
  for(int i = 0; i < 4; i++){
    const int r0 = i*16 + q*4;
#pragma unroll
    for(int j = 0; j < 4; j++){
      const int c = j*16 + m16;
      const int addr = c*64 + ((((r0 >> 3) ^ (c & 7)) << 3) | (r0 & 7));
      u32 lo = pack2bf(C[i][j][0]*s, C[i][j][1]*s);
      u32 hi = pack2bf(C[i][j][2]*s, C[i][j][3]*s);
      *(uint2*)(Pt + addr) = make_uint2(lo, hi);
    }
  }
}
__device__ __forceinline__ void write_CT_lds(u16* Pt, int lane, const f32x4 (&C)[4][4]){
  write_CT_lds_s(Pt, lane, C, 1.f);
}

// write C ROW-MAJOR swizzled (Zn), scaled — scalar scatter
__device__ __forceinline__ void scatter_C_rm(u16* Z, int lane, const f32x4 (&C)[4][4], float s){
  const int m16 = lane & 15, q = lane >> 4;
#pragma unroll
  for(int i = 0; i < 4; i++)
#pragma unroll
    for(int j = 0; j < 4; j++)
#pragma unroll
      for(int t = 0; t < 4; t++)
        Z[swz(i*16 + q*4 + t, j*16 + m16)] = f2bf(C[i][j][t]*s);
}

// ---------- partial (j-subrange) product pieces for 8-wave tree levels ----------
template<int NJ>
__device__ __forceinline__ void chain_part(const short8 (&Af)[2][4], const u16* Pt,
                                           int m16, int q, f32x4 (&C)[4][NJ], int j0){
  short8 Bf[2][NJ];
#pragma unroll
  for(int ks = 0; ks < 2; ks++)
#pragma unroll
    for(int j = 0; j < NJ; j++) Bf[ks][j] = lds_frag(Pt, (j0 + j)*16 + m16, ks*32 + q*8);
#pragma unroll
  for(int i = 0; i < 4; i++)
#pragma unroll
    for(int j = 0; j < NJ; j++) C[i][j] = f32x4{0.f,0.f,0.f,0.f};
#pragma unroll
  for(int ks = 0; ks < 2; ks++)
#pragma unroll
    for(int i = 0; i < 4; i++)
#pragma unroll
      for(int j = 0; j < NJ; j++)
        C[i][j] = mfma_bf16(Af[ks][i], Bf[ks][j], C[i][j]);
}
template<int NJ>
__device__ __forceinline__ void write_CT_part(u16* Pt, int lane, const f32x4 (&C)[4][NJ], int j0){
  const int m16 = lane & 15, q = lane >> 4;
#pragma unroll
  for(int i = 0; i < 4; i++){
    const int r0 = i*16 + q*4;
#pragma unroll
    for(int j = 0; j < NJ; j++){
      const int c = (j0 + j)*16 + m16;
      const int addr = c*64 + ((((r0 >> 3) ^ (c & 7)) << 3) | (r0 & 7));
      u32 lo = pack2bf(C[i][j][0], C[i][j][1]);
      u32 hi = pack2bf(C[i][j][2], C[i][j][3]);
      *(uint2*)(Pt + addr) = make_uint2(lo, hi);
    }
  }
}
template<int NJ>
__device__ __forceinline__ void scatter_part(u16* Z, int lane, const f32x4 (&C)[4][NJ], int j0){
  const int m16 = lane & 15, q = lane >> 4;
#pragma unroll
  for(int i = 0; i < 4; i++)
#pragma unroll
    for(int j = 0; j < NJ; j++)
#pragma unroll
      for(int t = 0; t < 4; t++)
        Z[swz(i*16 + q*4 + t, (j0 + j)*16 + m16)] = f2bf(C[i][j][t]);
}

// C = A (regs) * P (Pt = Zt of P); optional writeback of C^T into Pt (in-wave safe)
__device__ __forceinline__ void chain_step_A(const short8 (&Af)[2][4], u16* Pt, int lane,
                                             f32x4 (&C)[4][4], bool wb){
  const int m16 = lane & 15, q = lane >> 4;
  short8 Bf[2][4];
#pragma unroll
  for(int ks = 0; ks < 2; ks++)
#pragma unroll
    for(int t = 0; t < 4; t++) Bf[ks][t] = lds_frag(Pt, t*16 + m16, ks*32 + q*8);
#pragma unroll
  for(int i = 0; i < 4; i++)
#pragma unroll
    for(int j = 0; j < 4; j++) C[i][j] = f32x4{0.f,0.f,0.f,0.f};
#pragma unroll
  for(int ks = 0; ks < 2; ks++)
#pragma unroll
    for(int i = 0; i < 4; i++)
#pragma unroll
      for(int j = 0; j < 4; j++)
        C[i][j] = mfma_bf16(Af[ks][i], Bf[ks][j], C[i][j]);
  if(wb) write_CT_lds(Pt, lane, C);
}

__device__ __forceinline__ void ld_zn_frags(const u16* Zn, int m16, int q, short8 (&Af)[2][4]){
#pragma unroll
  for(int ks = 0; ks < 2; ks++)
#pragma unroll
    for(int t = 0; t < 4; t++) Af[ks][t] = lds_frag(Zn, t*16 + m16, ks*32 + q*8);
}
__device__ __forceinline__ void ld_bf16_frags(const u16* __restrict__ M, int m16, int q, short8 (&Af)[2][4]){
#pragma unroll
  for(int ks = 0; ks < 2; ks++)
#pragma unroll
    for(int t = 0; t < 4; t++) Af[ks][t] = g_frag(M, t*16 + m16, ks*32 + q*8);
}

// P = N (global row-major bf16) -> Zt of P
__device__ __forceinline__ void load_Pt_transpose(const u16* __restrict__ N, u16* Pt, int lane){
#pragma unroll
  for(int g = 0; g < 8; g++){
    short8 v = *(const short8*)(N + lane*64 + g*8);
#pragma unroll
    for(int t = 0; t < 8; t++) Pt[swz(g*8 + t, lane)] = (u16)v[t];
  }
}
// Pt <- Zt of an LDS Zn zone
__device__ __forceinline__ void lds_transpose(const u16* Z, u16* Pt, int lane){
#pragma unroll
  for(int g = 0; g < 8; g++){
    short8 f = lds_frag(Z, lane, g*8);
#pragma unroll
    for(int j = 0; j < 8; j++) Pt[swz(g*8 + j, lane)] = (u16)f[j];
  }
}

__device__ __forceinline__ float wave_max(float mx){
  for(int off = 32; off; off >>= 1) mx = fmaxf(mx, __shfl_xor(mx, off, 64));
  return mx;
}
__device__ __forceinline__ int norm_es(const f32x4 (&C)[4][4], float& s){
  float mx = 0.f;
#pragma unroll
  for(int i = 0; i < 4; i++)
#pragma unroll
    for(int j = 0; j < 4; j++)
#pragma unroll
      for(int t = 0; t < 4; t++) mx = fmaxf(mx, C[i][j][t]);   // entries all positive
  mx = wave_max(mx);
  int e; (void)frexpf(mx, &e);
  s = ldexpf(1.f, -e);
  return e;
}

// ---------- fence-free sync primitives ----------
// producer payloads go out write-through, __syncthreads drains vmcnt => stores
// complete at coherence point BEFORE the flag store is even issued.
__device__ __forceinline__ void set_flag(int* f){
  __syncthreads();
  if(threadIdx.x == 0) st_i32(f, 1);
}
__device__ __forceinline__ void add_ctr(int* c){
  __syncthreads();
  if(threadIdx.x == 0)
    __hip_atomic_fetch_add(c, 1, __ATOMIC_RELAXED, __HIP_MEMORY_SCOPE_AGENT);
}
// per-wave acquire polls (all 64 lanes spin on a wave-uniform address)
__device__ __forceinline__ void wave_poll(int* f){
  while(__hip_atomic_load(f, __ATOMIC_ACQUIRE, __HIP_MEMORY_SCOPE_AGENT) == 0)
    __builtin_amdgcn_s_sleep(1);
}
__device__ __forceinline__ void wave_poll_ge(int* c, int t){
  while(__hip_atomic_load(c, __ATOMIC_ACQUIRE, __HIP_MEMORY_SCOPE_AGENT) < t)
    __builtin_amdgcn_s_sleep(1);
}

// store a 64x64 node from LDS (Zn swizzled) to global: one dwordx4 WT store/thread
__device__ __forceinline__ void store_node_wt(const u16* Z, u16* __restrict__ out, int tid){
  int row = tid >> 3, c0 = (tid & 7)*8;
  short8 v = lds_frag(Z, row, c0);
  st_wt16(out + row*64 + c0, __builtin_bit_cast(u32x4, v));
}

// ---------- 8-wave tree levels L1+L2 over zones[0..7] (even idx Zt, odd idx Zn) ----------
// L1: product g = zones[2g+1]*zones[2g] -> zones[2g]   (wave pair 2g,2g+1; j-halves)
// L2: product p = zones[4p+2]*zones[4p] -> zones[4p]   (wave quad; j-quarters)
// read->barrier->write split makes the in-place zone update race-free across waves.
__device__ __forceinline__ void tree_L12(u16* zones, int lane, int wave){
  const int m16 = lane & 15, q = lane >> 4;
  {
    short8 Aa[2][4]; f32x4 Y[4][2];
    const int g = wave >> 1, j0 = (wave & 1)*2;
    ld_zn_frags(zones + (size_t)(2*g + 1)*4096, m16, q, Aa);
    chain_part<2>(Aa, zones + (size_t)(2*g)*4096, m16, q, Y, j0);
    __syncthreads();
    if(!(g & 1)) write_CT_part<2>(zones + (size_t)(2*g)*4096, lane, Y, j0);
    else         scatter_part<2>(zones + (size_t)(2*g)*4096, lane, Y, j0);
  }
  __syncthreads();
  {
    short8 Aa[2][4]; f32x4 Y[4][1];
    const int p = wave >> 2, j0 = wave & 3;
    ld_zn_frags(zones + (size_t)(4*p + 2)*4096, m16, q, Aa);
    chain_part<1>(Aa, zones + (size_t)(4*p)*4096, m16, q, Y, j0);
    __syncthreads();
    if(p == 0) write_CT_part<1>(zones, lane, Y, j0);
    else       scatter_part<1>(zones + (size_t)4*4096, lane, Y, j0);
  }
  __syncthreads();
}

// ==================== single kernel: 256 blocks x 512 threads, 1 block/CU ====================
// Block b processes seq chunk sig(b) = (b&15)*16 + (b>>4)  (XCD-local groups).
// Blocks 254,255: power iteration after phase A. Blocks 0..15: group combiners.
// Block 0: final 16->1 + contraction.
// Sync: per-node ready flags nf[256], per-M2 flags mfl[16], counters c2 (combiners
// done) and c3 (power blocks done). Consumers poll per-wave, start ASAP.
__global__ void __launch_bounds__(512) kall(const float* __restrict__ K, const int* __restrict__ seq,
                                            u16* __restrict__ Nbuf, u16* __restrict__ M2buf,
                                            int* __restrict__ Sarr, int* __restrict__ Earr,
                                            float* __restrict__ rhoR, float* __restrict__ rhoL,
                                            float* __restrict__ muv, int* __restrict__ bar,
                                            float* __restrict__ outp){
  __shared__ __align__(16) u16 Kl[8*4096];     // bf16 K (Zn swizzled)
  __shared__ __align__(16) u16 zones[8*4096];
  __shared__ __align__(16) u16 rhoZ[4096];
  __shared__ float redf[8];
  __shared__ int exps[8];
  __shared__ float sh_t2;
  __shared__ int sh_S;
  const int tid = threadIdx.x, lane = tid & 63, wave = tid >> 6, b = blockIdx.x;
  const int m16 = lane & 15, q = lane >> 4;
  const int sig = (b & 15)*16 + (b >> 4);
  u16* zw = zones + wave*4096;
  int* nf  = bar;          // [256] node-ready flags
  int* mfl = bar + 256;    // [16]  M2-ready flags
  int* c2  = bar + 272;    // combiners-done counter
  int* c3  = bar + 273;    // power-done counter

  // stage K[wave] fp32 -> Kl (Zn swizzled); lane owns row = lane
#pragma unroll
  for(int g = 0; g < 8; g++){
    const float* p = K + (size_t)wave*4096 + lane*64 + g*8;
    float4 a = *(const float4*)p, c = *(const float4*)(p + 4);
    u32x4 u = { pack2bf(a.x,a.y), pack2bf(a.z,a.w), pack2bf(c.x,c.y), pack2bf(c.z,c.w) };
    *(short8*)(Kl + wave*4096 + lane*64 + ((g ^ (lane & 7)) << 3)) = __builtin_bit_cast(short8, u);
  }
  int sv = (lane < 8) ? seq[sig*64 + wave*8 + lane] : 0;
  __syncthreads();

  // ================= PHASE A (all 256 blocks): node sig = 64 seq-mats =================
  {
    int s0 = __shfl(sv, 0, 64);
    lds_transpose(Kl + s0*4096, zw, lane);
    f32x4 C[4][4];
    short8 Af[2][4];
#pragma unroll 1
    for(int j = 1; j < 8; j++){
      int sj = __shfl(sv, j, 64);
      ld_zn_frags(Kl + sj*4096, m16, q, Af);
      chain_step_A(Af, zw, lane, C, j < 7);
    }
    { float s; int e = norm_es(C, s);
      if(!(wave & 1)) write_CT_lds_s(zw, lane, C, s);   // even wave -> Zt
      else            scatter_C_rm(zw, lane, C, s);     // odd wave  -> Zn
      if(lane == 0) exps[wave] = e; }
    __syncthreads();
    tree_L12(zones, lane, wave);                   // L1+L2, all 8 waves
    if(wave == 0){                                 // L3 + norm
      short8 Aa[2][4]; f32x4 M[4][4];
      ld_zn_frags(zones + 4*4096, m16, q, Aa);
      chain_step_A(Aa, zones, lane, M, false);
      float sr; int er = norm_es(M, sr);
      scatter_C_rm(zones, lane, M, sr);
      if(lane == 0){
        int ss = er;
#pragma unroll
        for(int w = 0; w < 8; w++) ss += exps[w];
        st_i32(&Sarr[sig], ss);
      }
    }
    __syncthreads();
    store_node_wt(zones, Nbuf + (size_t)sig*4096, tid);
  }
  set_flag(nf + sig);                              // node ready (stores drained)

  if(b >= 254){
    // ================= POWER (254=right, 255=left; parallel with combines) =================
    const bool left = (b == 255);
    short8 Kf[2][4];
    if(!left){
      ld_zn_frags(Kl + wave*4096, m16, q, Kf);
    } else {
#pragma unroll
      for(int ks = 0; ks < 2; ks++)
#pragma unroll
        for(int t = 0; t < 4; t++){
          short8 v;
#pragma unroll
          for(int j = 0; j < 8; j++) v[j] = (short)Kl[wave*4096 + swz(ks*32 + q*8 + j, t*16 + m16)];
          Kf[ks][t] = v;
        }
    }
    const int row = tid >> 3, k0 = (tid & 7)*8;
    const int rpos = row*64 + (((tid & 7) ^ (row & 7)) << 3);
    {
      short8 bb;
#pragma unroll
      for(int j = 0; j < 8; j++) bb[j] = (row == k0 + j) ? (short)f2bf(1.f/64.f) : (short)0;
      *(short8*)(rhoZ + rpos) = bb;
    }
    __syncthreads();
    const float S13 = 1.f/8192.f;        // fixed per-iter scale (lambda ~ 2^13)
#pragma unroll
    for(int it = 0; it < POWER_ITERS; it++){
      short8 Ar[2][4];
#pragma unroll
      for(int ks = 0; ks < 2; ks++)
#pragma unroll
        for(int t = 0; t < 4; t++) Ar[ks][t] = lds_frag(rhoZ, t*16 + m16, ks*32 + q*8);
      f32x4 C[4][4];
#pragma unroll
      for(int i = 0; i < 4; i++)
#pragma unroll
        for(int j = 0; j < 4; j++) C[i][j] = f32x4{0.f,0.f,0.f,0.f};
#pragma unroll
      for(int ks = 0; ks < 2; ks++)
#pragma unroll
        for(int i = 0; i < 4; i++)
#pragma unroll
          for(int j = 0; j < 4; j++)
            C[i][j] = mfma_bf16(Ar[ks][i], Kf[ks][j], C[i][j]);   // rho * Kdir^T
      write_CT_lds(zw, lane, C);
      short8 Bt[2][4];
#pragma unroll
      for(int ks = 0; ks < 2; ks++)
#pragma unroll
        for(int t = 0; t < 4; t++) Bt[ks][t] = lds_frag(zw, t*16 + m16, ks*32 + q*8);
#pragma unroll
      for(int i = 0; i < 4; i++)
#pragma unroll
        for(int j = 0; j < 4; j++) C[i][j] = f32x4{0.f,0.f,0.f,0.f};
#pragma unroll
      for(int ks = 0; ks < 2; ks++)
#pragma unroll
        for(int i = 0; i < 4; i++)
#pragma unroll
          for(int j = 0; j < 4; j++)
            C[i][j] = mfma_bf16(Kf[ks][i], Bt[ks][j], C[i][j]);   // Kdir * (..)^T
      write_CT_lds(zw, lane, C);
      __syncthreads();
      float v[8];
#pragma unroll
      for(int j2 = 0; j2 < 8; j2++) v[j2] = 0.f;
#pragma unroll
      for(int z = 0; z < 8; z++){
        short8 f = lds_frag(zones + z*4096, row, k0);
#pragma unroll
        for(int j2 = 0; j2 < 8; j2++) v[j2] += bf2f((u16)f[j2]);
      }
      if(it != POWER_ITERS - 1){
        u32x4 u = { pack2bf(v[0]*S13, v[1]*S13), pack2bf(v[2]*S13, v[3]*S13),
                    pack2bf(v[4]*S13, v[5]*S13), pack2bf(v[6]*S13, v[7]*S13) };
        *(short8*)(rhoZ + rpos) = __builtin_bit_cast(short8, u);
        __syncthreads();
      } else {
        float pd = (k0 <= row && row < k0 + 8) ? v[row - k0] : 0.f;
        for(int off = 32; off; off >>= 1) pd += __shfl_xor(pd, off, 64);
        if(lane == 0) redf[wave] = pd;
        __syncthreads();
        float tr = 0.f;
#pragma unroll
        for(int w = 0; w < 8; w++) tr += redf[w];
        float inv = 1.f/tr;
        float* ro = left ? rhoL : rhoR;
        f32x4 w0 = { v[0]*inv, v[1]*inv, v[2]*inv, v[3]*inv };
        f32x4 w1 = { v[4]*inv, v[5]*inv, v[6]*inv, v[7]*inv };
        st_wt16(ro + row*64 + k0,     __builtin_bit_cast(u32x4, w0));
        st_wt16(ro + row*64 + k0 + 4, __builtin_bit_cast(u32x4, w1));
        u32x4 u = { pack2bf(v[0]*inv, v[1]*inv), pack2bf(v[2]*inv, v[3]*inv),
                    pack2bf(v[4]*inv, v[5]*inv), pack2bf(v[6]*inv, v[7]*inv) };
        *(short8*)(rhoZ + rpos) = __builtin_bit_cast(short8, u);   // normalized bf16 in LDS
        __syncthreads();
      }
    }
    if(left){
      // lambda = tr(rho_l * sum_a K_a K_a^T); wave a handles K_a
      short8 Ka[2][4];
      ld_zn_frags(Kl + wave*4096, m16, q, Ka);
      f32x4 G[4][4];
#pragma unroll
      for(int i = 0; i < 4; i++)
#pragma unroll
        for(int j = 0; j < 4; j++) G[i][j] = f32x4{0.f,0.f,0.f,0.f};
#pragma unroll
      for(int ks = 0; ks < 2; ks++)
#pragma unroll
        for(int i = 0; i < 4; i++)
#pragma unroll
          for(int j = 0; j < 4; j++)
            G[i][j] = mfma_bf16(Ka[ks][i], Ka[ks][j], G[i][j]);
      float lp = 0.f;
#pragma unroll
      for(int i = 0; i < 4; i++)
#pragma unroll
        for(int j = 0; j < 4; j++)
#pragma unroll
          for(int t = 0; t < 4; t++){
            int r = i*16 + q*4 + t, c = j*16 + m16;
            lp += G[i][j][t] * bf2f(rhoZ[swz(r, c)]);
          }
      for(int off = 32; off; off >>= 1) lp += __shfl_xor(lp, off, 64);
      if(lane == 0) redf[wave] = lp;
      __syncthreads();
      if(tid == 0){
        float m = 0.f;
#pragma unroll
        for(int w = 0; w < 8; w++) m += redf[w];
        st_f32(muv, m);
      }
    }
    add_ctr(c3);                                   // rho/mu published (drained)
  }

  if(b < 16){
    // ================= COMBINE: group b's 16 nodes -> M2buf[b] =================
    const int nb = b*16;
    wave_poll(nf + nb + 2*wave);                   // only the pair THIS wave needs
    wave_poll(nf + nb + 2*wave + 1);
    short8 Af[2][4];
    f32x4 C[4][4];
    ld_bf16_frags(Nbuf + (size_t)(nb + 2*wave + 1)*4096, m16, q, Af);
    load_Pt_transpose(Nbuf + (size_t)(nb + 2*wave)*4096, zw, lane);
    chain_step_A(Af, zw, lane, C, false);
    { float s; int e = norm_es(C, s);
      if(!(wave & 1)) write_CT_lds_s(zw, lane, C, s);
      else            scatter_C_rm(zw, lane, C, s);
      if(lane == 0) exps[wave] = e; }
    __syncthreads();
    tree_L12(zones, lane, wave);
    if(wave == 0){
      short8 Aa[2][4]; f32x4 M[4][4];
      ld_zn_frags(zones + 4*4096, m16, q, Aa);
      chain_step_A(Aa, zones, lane, M, false);
      float sr; int er = norm_es(M, sr);
      scatter_C_rm(zones, lane, M, sr);
      if(lane == 0){
        int ss = er;
#pragma unroll
        for(int w = 0; w < 8; w++) ss += exps[w];
        st_i32(&Earr[b], ss);
      }
    }
    __syncthreads();
    store_node_wt(zones, M2buf + (size_t)b*4096, tid);
    __syncthreads();                               // drain M2 stores
    if(tid == 0){
      st_i32(mfl + b, 1);
      __hip_atomic_fetch_add(c2, 1, __ATOMIC_RELAXED, __HIP_MEMORY_SCOPE_AGENT);
    }
  }

  if(b == 0){
    // ================= FINAL =================
    wave_poll(mfl + 2*wave);                       // per-wave fine-grained start
    wave_poll(mfl + 2*wave + 1);
    short8 Af[2][4];
    f32x4 C[4][4];
    ld_bf16_frags(M2buf + (size_t)(2*wave + 1)*4096, m16, q, Af);
    load_Pt_transpose(M2buf + (size_t)(2*wave)*4096, zw, lane);
    chain_step_A(Af, zw, lane, C, false);
    { float s; int e = norm_es(C, s);
      if(!(wave & 1)) write_CT_lds_s(zw, lane, C, s);
      else            scatter_C_rm(zw, lane, C, s);
      if(lane == 0) exps[wave] = e; }
    __syncthreads();
    // L1 (waves 0-3) + side jobs (waves 4,5,6)
    if(wave < 4){
      short8 Aa[2][4]; f32x4 Y[4][4];
      ld_zn_frags(zones + (2*wave + 1)*4096, m16, q, Aa);
      bool e2 = !(wave & 1);
      chain_step_A(Aa, zones + 2*wave*4096, lane, Y, e2);
      if(!e2) scatter_C_rm(zones + 2*wave*4096, lane, Y, 1.f);
    } else if(wave == 4){
      wave_poll_ge(c3, 2);                         // rhoR/rhoL published
      float t2 = 0.f;
      for(int j = 0; j < 64; j++){
        int idx = lane + 64*j;
        t2 += rhoR[idx] * rhoL[idx];
      }
      for(int off = 32; off; off >>= 1) t2 += __shfl_xor(t2, off, 64);
      if(lane == 0) sh_t2 = t2;
    } else if(wave == 5){
      wave_poll_ge(c2, 16);                        // all Sarr/Earr published
      int s = Sarr[lane] + Sarr[lane + 64] + Sarr[lane + 128] + Sarr[lane + 192];
      if(lane < 16) s += Earr[lane];
      for(int off = 32; off; off >>= 1) s += __shfl_xor(s, off, 64);
      if(lane == 0) sh_S = s;
    } else if(wave == 6){
      wave_poll_ge(c3, 2);
      // rho_r fp32 -> rhoZ (Zn bf16; symmetric)
#pragma unroll
      for(int g = 0; g < 8; g++){
        const float* p = rhoR + lane*64 + g*8;
        float4 a = *(const float4*)p, c = *(const float4*)(p + 4);
        u32x4 u = { pack2bf(a.x,a.y), pack2bf(a.z,a.w), pack2bf(c.x,c.y), pack2bf(c.z,c.w) };
        *(short8*)(rhoZ + lane*64 + ((g ^ (lane & 7)) << 3)) = __builtin_bit_cast(short8, u);
      }
    }
    __syncthreads();
    // L2 (waves 0,1); wave2: rho_l -> zone3 (free after L1)
    if(wave < 2){
      short8 Aa[2][4]; f32x4 Y[4][4];
      ld_zn_frags(zones + (4*wave + 2)*4096, m16, q, Aa);
      chain_step_A(Aa, zones + 4*wave*4096, lane, Y, wave == 0);
      if(wave == 1) scatter_C_rm(zones + 4*4096, lane, Y, 1.f);
    } else if(wave == 2){
      wave_poll_ge(c3, 2);
#pragma unroll
      for(int g = 0; g < 8; g++){
        const float* p = rhoL + lane*64 + g*8;
        float4 a = *(const float4*)p, c = *(const float4*)(p + 4);
        u32x4 u = { pack2bf(a.x,a.y), pack2bf(a.z,a.w), pack2bf(c.x,c.y), pack2bf(c.z,c.w) };
        *(short8*)(zones + 3*4096 + lane*64 + ((g ^ (lane & 7)) << 3)) = __builtin_bit_cast(short8, u);
      }
    }
    __syncthreads();
    // L3 + contraction (wave 0)
    if(wave == 0){
      wave_poll_ge(c3, 2);                         // muv published (cheap, already set)
      short8 Aa[2][4];
      ld_zn_frags(zones + 4*4096, m16, q, Aa);
      chain_step_A(Aa, zones, lane, C, false);
      float sM; int eM = norm_es(C, sM);
      u16* Pm = zones + 1*4096;                    // free zone
      scatter_C_rm(Pm, lane, C, sM);               // M (Zn)

      // U = M * rho_r -> U^T in zone2
      short8 Ua[2][4], Ub[2][4];
      ld_zn_frags(Pm, m16, q, Ua);
      ld_zn_frags(rhoZ, m16, q, Ub);
#pragma unroll
      for(int i = 0; i < 4; i++)
#pragma unroll
        for(int j = 0; j < 4; j++) C[i][j] = f32x4{0.f,0.f,0.f,0.f};
#pragma unroll
      for(int ks = 0; ks < 2; ks++)
#pragma unroll
        for(int i = 0; i < 4; i++)
#pragma unroll
          for(int j = 0; j < 4; j++)
            C[i][j] = mfma_bf16(Ua[ks][i], Ub[ks][j], C[i][j]);
      write_CT_lds(zones + 2*4096, lane, C);

      // D2 = rho_l * U
      ld_zn_frags(zones + 3*4096, m16, q, Ua);
#pragma unroll
      for(int ks = 0; ks < 2; ks++)
#pragma unroll
        for(int t = 0; t < 4; t++) Ub[ks][t] = lds_frag(zones + 2*4096, t*16 + m16, ks*32 + q*8);
#pragma unroll
      for(int i = 0; i < 4; i++)
#pragma unroll
        for(int j = 0; j < 4; j++) C[i][j] = f32x4{0.f,0.f,0.f,0.f};
#pragma unroll
      for(int ks = 0; ks < 2; ks++)
#pragma unroll
        for(int i = 0; i < 4; i++)
#pragma unroll
          for(int j = 0; j < 4; j++)
            C[i][j] = mfma_bf16(Ua[ks][i], Ub[ks][j], C[i][j]);

      // t1 = sum_ij D2_ij * M_ij
      float part = 0.f;
#pragma unroll
      for(int i = 0; i < 4; i++)
#pragma unroll
        for(int j = 0; j < 4; j++)
#pragma unroll
          for(int t = 0; t < 4; t++){
            int r = i*16 + q*4 + t, c = j*16 + m16;
            part += C[i][j][t] * bf2f(Pm[swz(r, c)]);
          }
      for(int off = 32; off; off >>= 1) part += __shfl_xor(part, off, 64);
      if(lane == 0){
        double t1  = (double)part;
        double lam = (double)muv[0];
        double S   = (double)sh_S + eM;
#pragma unroll
        for(int w = 0; w < 8; w++) S += exps[w];
        double logp = 16384.0*log2(lam) - 2.0*S - log2(t1) + log2((double)sh_t2);
        outp[0] = (float)logp;
      }
    }
  }
}

// ---------- launch ----------
extern "C" void kernel_launch(void* const* d_in, const int* in_sizes, int n_in,
                              void* d_out, int out_size, void* d_ws, size_t ws_size,
                              hipStream_t stream) {
  const float* K  = (const float*)d_in[0];   // (8,64,64) fp32
  const int* seq  = (const int*)d_in[1];     // (16384,) int32
  char* ws = (char*)d_ws;
  u16*   Nbuf  = (u16*)(ws);                   // 256 * 8KB = 2 MB
  u16*   M2buf = (u16*)(ws + 2097152);         // 16 * 8KB = 128 KB
  int*   Sarr  = (int*)(ws + 2228224);         // 256 ints
  int*   Earr  = (int*)(ws + 2229248);         // 16 ints
  float* rhoR  = (float*)(ws + 2229760);       // 16 KB
  float* rhoL  = (float*)(ws + 2246144);       // 16 KB
  float* muv   = (float*)(ws + 2262528);       // 1 float
  int*   bar   = (int*)(ws + 2262592);         // nf[256] + mfl[16] + c2 + c3

  hipMemsetAsync(bar, 0, 274*4, stream);
  kall<<<256, 512, 0, stream>>>(K, seq, Nbuf, M2buf, Sarr, Earr, rhoR, rhoL, muv, bar,
                                (float*)d_out);
}